// Round 4
// baseline (1161.103 us; speedup 1.0000x reference)
//
#include <hip/hip_runtime.h>

// HyperConv: y[b,o,t] = sum_{i<3} sum_{c<16} x[b,c,t+8-4i] * w_b[i*16+c][o]
// w_b = LeakyReLU(p[b]@W1 + b1) @ W2 + b2, reshaped [48][16].
//
// R4: persistent-wave streaming test. R0 (reg loads) / R2 (LDS pipeline) /
// R3 (16KB bursts) all pinned at 2.2-2.4 TB/s mixed BW => pipeline depth,
// barriers, burst length, store policy falsified. Last untested copy-bench
// property: sustained waves (continuous load/store interleave, no phased
// single-shot blocks) + XCD-chunked window locality. Each block now owns 2
// consecutive 1024-t tiles (cross-tile ILP: tile-1 loads overlap tile-0
// stores), weights computed once per block, XCDs own contiguous 1/8 slabs.
// If this is again within +-5% of 87 us/dispatch: declare roofline.

#define NB 32
#define IN_CH 16
#define OUT_CH 16
#define KW 3
#define DIL 4
#define COND 8
#define T_OUT 65536
#define PADT 8
#define XT (T_OUT + PADT)            // 65544 floats, row stride of x
#define W2COLS (IN_CH * OUT_CH * KW) // 768
#define TPB 256
#define TPT 4                        // t-positions per thread
#define T_PER_TILE (TPB * TPT)       // 1024
#define TILES_PER_B (T_OUT / T_PER_TILE) // 64
#define NTILES (NB * TILES_PER_B)    // 2048
#define NITER 2                      // tiles per block (consecutive)
#define GRID (NTILES / NITER)        // 1024 blocks = 4/CU, 16 waves/CU
#define NXCD 8
#define TILES_PER_XCD (NTILES / NXCD) // 256

typedef float f32x4 __attribute__((ext_vector_type(4)));

__global__ __launch_bounds__(TPB)
void hyperconv_kernel(const float* __restrict__ x,
                      const float* __restrict__ p,
                      const float* __restrict__ W1,
                      const float* __restrict__ b1,
                      const float* __restrict__ W2,
                      const float* __restrict__ b2,
                      float* __restrict__ y)
{
    __shared__ float h_lds[IN_CH];
    __shared__ __align__(16) float w_lds[W2COLS];   // 3 KiB

    const int tid = threadIdx.x;
    const int bid = blockIdx.x;

    // XCD-chunked swizzle: default round-robin sends bid%8 -> XCD (bid&7).
    // Give XCD k the contiguous tile slab [k*256, (k+1)*256): compact x/y
    // window per XCD L2. Bijective: 8 * 128 locals * 2 tiles = 2048 tiles.
    const int xcd   = bid & (NXCD - 1);
    const int local = bid >> 3;                      // 0..127
    const int cid0  = xcd * TILES_PER_XCD + local * NITER;
    const int b     = cid0 >> 6;                     // same b for both tiles

    // ---- hypernetwork: h = LeakyReLU(p[b] @ W1 + b1) ----
    if (tid < IN_CH) {
        float acc = b1[tid];
#pragma unroll
        for (int j = 0; j < COND; ++j)
            acc += p[b * COND + j] * W1[j * IN_CH + tid];
        h_lds[tid] = acc > 0.f ? acc : 0.2f * acc;
    }
    __syncthreads();

    // ---- w = h @ W2 + b2 : 768 entries, 3 per thread ----
#pragma unroll
    for (int r = 0; r < 3; ++r) {
        const int n = tid * 3 + r;
        float acc = b2[n];
#pragma unroll
        for (int c = 0; c < IN_CH; ++c)
            acc += h_lds[c] * W2[c * W2COLS + n];
        w_lds[n] = acc;
    }
    __syncthreads();   // only barrier; w_lds is read-only afterwards

    // ---- 2 consecutive tiles per block; no barriers between tiles, so the
    //      scheduler can overlap tile-1 loads with tile-0 FMAs/stores ----
#pragma unroll
    for (int j = 0; j < NITER; ++j) {
        const int tc = (cid0 + j) & (TILES_PER_B - 1);
        const int t0 = tc * T_PER_TILE + tid * TPT;
        const float* xb = x + (size_t)b * IN_CH * XT + t0;

        float4 acc[OUT_CH];
#pragma unroll
        for (int o = 0; o < OUT_CH; ++o) acc[o] = make_float4(0.f, 0.f, 0.f, 0.f);

#pragma unroll
        for (int c = 0; c < IN_CH; ++c) {
            // taps: x index = t + 8 - 4*i ; i=2 -> +0, i=1 -> +4, i=0 -> +8
            const float4 a0 = *(const float4*)(xb + c * XT);      // i = 2
            const float4 a1 = *(const float4*)(xb + c * XT + 4);  // i = 1
            const float4 a2 = *(const float4*)(xb + c * XT + 8);  // i = 0
            const float4 vs[KW] = {a2, a1, a0};                   // indexed by i
#pragma unroll
            for (int i = 0; i < KW; ++i) {
                const float4 v = vs[i];
                const float* wrow = &w_lds[(i * IN_CH + c) * OUT_CH];
#pragma unroll
                for (int og = 0; og < 4; ++og) {
                    const float4 wv = *(const float4*)(wrow + og * 4);
                    float4* a = &acc[og * 4];
                    a[0].x += v.x * wv.x; a[0].y += v.y * wv.x;
                    a[0].z += v.z * wv.x; a[0].w += v.w * wv.x;
                    a[1].x += v.x * wv.y; a[1].y += v.y * wv.y;
                    a[1].z += v.z * wv.y; a[1].w += v.w * wv.y;
                    a[2].x += v.x * wv.z; a[2].y += v.y * wv.z;
                    a[2].z += v.z * wv.z; a[2].w += v.w * wv.z;
                    a[3].x += v.x * wv.w; a[3].y += v.y * wv.w;
                    a[3].z += v.z * wv.w; a[3].w += v.w * wv.w;
                }
            }
        }

        float* yb = y + (size_t)b * OUT_CH * T_OUT + t0;
#pragma unroll
        for (int o = 0; o < OUT_CH; ++o) {
            const float4 a = acc[o];
            f32x4 v = {a.x, a.y, a.z, a.w};
            __builtin_nontemporal_store(v, (f32x4*)(yb + o * T_OUT));
        }
    }
}

extern "C" void kernel_launch(void* const* d_in, const int* in_sizes, int n_in,
                              void* d_out, int out_size, void* d_ws, size_t ws_size,
                              hipStream_t stream) {
    const float* x  = (const float*)d_in[0];
    const float* p  = (const float*)d_in[1];
    const float* W1 = (const float*)d_in[2];
    const float* b1 = (const float*)d_in[3];
    const float* W2 = (const float*)d_in[4];
    const float* b2 = (const float*)d_in[5];
    float* y = (float*)d_out;

    dim3 grid(GRID);    // 1024 blocks, 4 per CU
    dim3 block(TPB);
    hyperconv_kernel<<<grid, block, 0, stream>>>(x, p, W1, b1, W2, b2, y);
}

// Round 5
// 269.533 us; speedup vs baseline: 4.3078x; 4.3078x over previous
//
#include <hip/hip_runtime.h>

// HyperConv: y[b,o,t] = sum_{i<3} sum_{c<16} x[b,c,t+8-4i] * w_b[i*16+c][o]
// w_b = LeakyReLU(p[b]@W1 + b1) @ W2 + b2, reshaped [48][16].
//
// R5: launch-rate theory. All 87us variants (R0 reg-loads, R2 LDS pipeline,
// R3 16KB bursts) launch exactly 8192 waves; occupancy reads 24-37% despite
// resources allowing 100%; Little's law gives block lifetime ~26us => wave
// START rate (~1/25cy) is the limiter, not memory. Fix: 512 persistent
// blocks (2048 waves, 2/CU), each runs ONE continuous 64-row rolling
// pipeline over 4 tiles (stage row r+3 while computing row r, counted
// per-wave vmcnt, raw s_barrier). Store batches are counted into the vmcnt
// immediates for the 3 iterations they shadow. Outer loop unroll(1) —
// R4's spill came from unrolling across the 64-VGPR accumulator block.

#define NB 32
#define IN_CH 16
#define OUT_CH 16
#define KW 3
#define COND 8
#define T_OUT 65536
#define PADT 8
#define XT (T_OUT + PADT)            // 65544 floats, row stride of x
#define W2COLS (IN_CH * OUT_CH * KW) // 768
#define TPB 256
#define TPT 4                        // t-positions per thread
#define T_PER_TILE (TPB * TPT)       // 1024
#define TILES_PER_B (T_OUT / T_PER_TILE) // 64
#define GROUPS 16                    // blocks per batch sample
#define TILES_PER_BLOCK (TILES_PER_B / GROUPS) // 4
#define NR (TILES_PER_BLOCK * IN_CH) // 64 pipeline rows per block
#define ROWF (T_PER_TILE + PADT)     // 1032 floats staged per row
#define NBUF 4                       // rolling buffers (distance-3 prefetch)
#define GRID (NB * GROUPS)           // 512 blocks = 2/CU, 2048 waves total

typedef const __attribute__((address_space(1))) void* gvp;
typedef __attribute__((address_space(3))) void* svp;
typedef float f32x4 __attribute__((ext_vector_type(4)));

// Stage one 1032-float row into LDS: wave w covers bytes [w*1024,(w+1)*1024)
// (linear dest = base+lane*16 per global_load_lds semantics); wave 0 lanes
// 0..1 add the 8-float halo. => 1 vmem op/row/wave (2 for wave 0).
__device__ __forceinline__ void stage_row(const float* __restrict__ g,
                                          float* l, int wid, int lane)
{
    __builtin_amdgcn_global_load_lds((gvp)(g + wid * 256 + lane * 4),
                                     (svp)(l + wid * 256), 16, 0, 0);
    if (wid == 0 && lane < 2)
        __builtin_amdgcn_global_load_lds((gvp)(g + T_PER_TILE + lane * 4),
                                         (svp)(l + T_PER_TILE), 16, 0, 0);
}

// One channel-row: 3 taps x 16 outputs x 4 t = 192 FMA/thread.
__device__ __forceinline__ void compute_row(const float* __restrict__ xrow,
                                            const float* __restrict__ w_lds,
                                            int c, float4* acc, int tid)
{
    const float4 l0 = *(const float4*)(xrow + tid * 4);      // tap i=2 (+0)
    const float4 l1 = *(const float4*)(xrow + tid * 4 + 4);  // tap i=1 (+4)
    const float4 l2 = *(const float4*)(xrow + tid * 4 + 8);  // tap i=0 (+8)
    const float4 vs[KW] = {l2, l1, l0};                      // vs[i]: offset 8-4i
#pragma unroll
    for (int i = 0; i < KW; ++i) {
        const float4 v = vs[i];
        const float* wrow = w_lds + (i * IN_CH + c) * OUT_CH;
#pragma unroll
        for (int og = 0; og < 4; ++og) {
            const float4 wv = *(const float4*)(wrow + og * 4);
            float4* a = acc + og * 4;
            a[0].x += v.x * wv.x; a[0].y += v.y * wv.x;
            a[0].z += v.z * wv.x; a[0].w += v.w * wv.x;
            a[1].x += v.x * wv.y; a[1].y += v.y * wv.y;
            a[1].z += v.z * wv.y; a[1].w += v.w * wv.y;
            a[2].x += v.x * wv.z; a[2].y += v.y * wv.z;
            a[2].z += v.z * wv.z; a[2].w += v.w * wv.z;
            a[3].x += v.x * wv.w; a[3].y += v.y * wv.w;
            a[3].z += v.z * wv.w; a[3].w += v.w * wv.w;
        }
    }
}

__global__ __launch_bounds__(TPB)
void hyperconv_kernel(const float* __restrict__ x,
                      const float* __restrict__ p,
                      const float* __restrict__ W1,
                      const float* __restrict__ b1,
                      const float* __restrict__ W2,
                      const float* __restrict__ b2,
                      float* __restrict__ y)
{
    __shared__ __align__(16) float xbuf[NBUF][ROWF];  // 16.1 KiB
    __shared__ float h_lds[IN_CH];
    __shared__ __align__(16) float w_lds[W2COLS];     // 3 KiB

    const int tid   = threadIdx.x;
    const int wid   = tid >> 6;
    const int lane  = tid & 63;
    const int b     = blockIdx.x >> 4;   // 0..31
    const int group = blockIdx.x & 15;   // 0..15; tiles group+16j, j=0..3

    const float* xb_base = x + (size_t)b * IN_CH * XT;

    // row r -> tile j=r>>4, channel c=r&15
#define ROW_PTR(r) (xb_base + (size_t)((r) & 15) * XT \
                    + (group + GROUPS * ((r) >> 4)) * T_PER_TILE)

    // Prologue: rows 0..2 in flight under the hypernet phase.
    stage_row(ROW_PTR(0), xbuf[0], wid, lane);
    stage_row(ROW_PTR(1), xbuf[1], wid, lane);
    stage_row(ROW_PTR(2), xbuf[2], wid, lane);

    // ---- hypernetwork: h = LeakyReLU(p[b] @ W1 + b1) ----
    if (tid < IN_CH) {
        float acc = b1[tid];
#pragma unroll
        for (int j = 0; j < COND; ++j)
            acc += p[b * COND + j] * W1[j * IN_CH + tid];
        h_lds[tid] = acc > 0.f ? acc : 0.2f * acc;
    }
    __syncthreads();

    // ---- w = h @ W2 + b2 : 768 entries, 3 per thread ----
#pragma unroll
    for (int r = 0; r < 3; ++r) {
        const int n = tid * 3 + r;
        float acc = b2[n];
#pragma unroll
        for (int c = 0; c < IN_CH; ++c)
            acc += h_lds[c] * W2[c * W2COLS + n];
        w_lds[n] = acc;
    }
    __syncthreads();   // drains vmcnt(0): rows 0..2 resident, clean baseline

    float4 acc[OUT_CH];
#pragma unroll
    for (int o = 0; o < OUT_CH; ++o) acc[o] = make_float4(0.f, 0.f, 0.f, 0.f);

    // ---- continuous 64-row pipeline across 4 tiles ----
    // vmcnt bookkeeping (per wave, in-order): steady state after stage(r+3)
    // the wave has loads r+1..r+3 outstanding (E=1 op/row, E=2 for wave 0).
    // A 16-op store batch issued at iter 16j+15 is younger than load r for
    // r%16 in {0,1,2} (r>=16) -> widen those waits by +16.
#pragma unroll 1
    for (int r = 0; r < NR; ++r) {
        __builtin_amdgcn_sched_barrier(0);
        if (r + 3 < NR)
            stage_row(ROW_PTR(r + 3), xbuf[(r + 3) & 3], wid, lane);
        if (r >= NR - 3) {
            asm volatile("s_waitcnt vmcnt(0)" ::: "memory");
        } else if ((r & 15) < 3 && r >= 16) {
            if (wid == 0) asm volatile("s_waitcnt vmcnt(22)" ::: "memory");
            else          asm volatile("s_waitcnt vmcnt(19)" ::: "memory");
        } else {
            if (wid == 0) asm volatile("s_waitcnt vmcnt(6)" ::: "memory");
            else          asm volatile("s_waitcnt vmcnt(3)" ::: "memory");
        }
        __builtin_amdgcn_s_barrier();            // row r landed for all waves
        __builtin_amdgcn_sched_barrier(0);
        compute_row(xbuf[r & 3], w_lds, r & 15, acc, tid);
        __builtin_amdgcn_sched_barrier(0);
        if ((r & 15) == 15) {                    // tile finished: store + reset
            float* yb = y + (size_t)b * OUT_CH * T_OUT
                      + (group + GROUPS * (r >> 4)) * T_PER_TILE + tid * TPT;
#pragma unroll
            for (int o = 0; o < OUT_CH; ++o) {
                const float4 a = acc[o];
                f32x4 v = {a.x, a.y, a.z, a.w};
                __builtin_nontemporal_store(v, (f32x4*)(yb + o * T_OUT));
                acc[o] = make_float4(0.f, 0.f, 0.f, 0.f);
            }
        }
        __builtin_amdgcn_s_barrier();            // readers done before overwrite
    }
#undef ROW_PTR
}

extern "C" void kernel_launch(void* const* d_in, const int* in_sizes, int n_in,
                              void* d_out, int out_size, void* d_ws, size_t ws_size,
                              hipStream_t stream) {
    const float* x  = (const float*)d_in[0];
    const float* p  = (const float*)d_in[1];
    const float* W1 = (const float*)d_in[2];
    const float* b1 = (const float*)d_in[3];
    const float* W2 = (const float*)d_in[4];
    const float* b2 = (const float*)d_in[5];
    float* y = (float*)d_out;

    dim3 grid(GRID);    // 512 blocks, 2 per CU, 2048 waves
    dim3 block(TPB);
    hyperconv_kernel<<<grid, block, 0, stream>>>(x, p, W1, b1, W2, b2, y);
}